// Round 16
// baseline (193.719 us; speedup 1.0000x reference)
//
#include <hip/hip_runtime.h>
#include <hip/hip_cooperative_groups.h>

namespace cg = cooperative_groups;

#define CLG_NATOMS 8192
#define CLG_NSHIFT 14
#define CLG_NROWS (CLG_NSHIFT * CLG_NATOMS)  // 114688 rows = (k, i)
#define CLG_NTILE 112                        // scan tiles of 1024 rows
#define CLG_NCELL 512                        // 8x8x8 spatial bins
#define CLG_CAP 128                          // max hits per row (k=0 max ~90)
#define CLG_NBLK 256                         // cooperative grid: 256 x 512
#define CLG_NTHR 512
#define CLG_GSIZE (CLG_NBLK * CLG_NTHR)      // 131072 threads
#define CLG_NWAVES (CLG_GSIZE / 64)          // 2048 waves
#define CLG_C2 ((float)(5.2 * 5.2))          // f32 compare (JAX weak promotion)
#define CLG_R 5.35f                          // candidate interval half-width

__device__ const int clg_shifts[CLG_NSHIFT][3] = {
    {0, 0, 0},
    {-1, 0, 0}, {-1, -1, 0}, {0, -1, 0}, {1, -1, 0},
    {-1, 1, -1}, {0, 1, -1}, {1, 1, -1}, {-1, 0, -1},
    {0, 0, -1}, {1, 0, -1}, {-1, -1, -1}, {0, -1, -1}, {1, -1, -1}};

// Module-owned scratch (d_ws unused). Everything read is rewritten each call.
__device__ float4 clg_pp[CLG_NATOMS];      // wrapped coords
__device__ int clg_cid[CLG_NATOMS];        // cell id per atom
__device__ float4 clg_sorted[CLG_NATOMS];  // bin-sorted coords, .w = original i
__device__ unsigned clg_cstart[CLG_NCELL + 1];
__device__ unsigned clg_cfill[CLG_NCELL];
__device__ unsigned clg_nalive;            // alive-row count (reset in P0)
__device__ unsigned clg_alist[CLG_NROWS];  // alive row ids (k<<13 | i)
__device__ int clg_jbuf[(size_t)CLG_NROWS * CLG_CAP];  // per-row sorted hit j's
__device__ unsigned clg_cnt[CLG_NROWS];
__device__ unsigned clg_off[CLG_NROWS];    // exclusive offset WITHIN tile
__device__ unsigned clg_tot[CLG_NTILE];    // per-tile totals
__device__ float4 clg_dg;                  // cell diagonal
__device__ float4 clg_cinv;                // 8/diag per axis
__device__ float4 clg_sf[CLG_NSHIFT];      // s * diag (f32, __fmul_rn)

// Slab prune: d2<=c2 forces shifted atom i into a cutoff-wide boundary slab.
__device__ __forceinline__ bool clg_alive_f(float xi, float yi, float zi, int sx,
                                            int sy, int sz, float dgx, float dgy,
                                            float dgz) {
  bool a = true;
  if (sx < 0) a = a && (xi >= dgx - 5.3f); else if (sx > 0) a = a && (xi <= 5.3f);
  if (sy < 0) a = a && (yi >= dgy - 5.3f); else if (sy > 0) a = a && (yi <= 5.3f);
  if (sz < 0) a = a && (zi >= dgz - 5.3f); else if (sz > 0) a = a && (zi <= 5.3f);
  return a;
}

// Candidate cell range on one axis (monotone-rounding safe, 0.14 slack).
__device__ __forceinline__ void clg_crange(float t, float ci, int& lo, int& hi) {
  lo = max(0, (int)(fmaxf(t - CLG_R, 0.f) * ci));
  hi = min(7, (int)(fmaxf(t + CLG_R, 0.f) * ci));
}

__device__ __forceinline__ unsigned clg_iscan(unsigned v, int lane) {
  for (int off = 1; off < 64; off <<= 1) {
    unsigned t = __shfl_up(v, off);
    if (lane >= off) v += t;
  }
  return v;
}

__global__ __launch_bounds__(CLG_NTHR) void clg_fused(const float* __restrict__ coords,
                                                      const float* __restrict__ cell,
                                                      int* __restrict__ out, int P) {
  cg::grid_group grid = cg::this_grid();
  __shared__ union {
    unsigned h[CLG_NCELL];   // P1 hist/scan
    uint4 smask[8][64];      // P3 per-wave masks (8 KB)
    unsigned sd[CLG_NTHR];   // P4 tile scan
  } shm;

  int tid = threadIdx.x;
  int gid = blockIdx.x * CLG_NTHR + tid;
  int lane = tid & 63;
  int wslot = tid >> 6;

  // ---- P0: wrap + cell-id; zero cnt; reset nalive; publish constants ------
  if (gid < CLG_NROWS) clg_cnt[gid] = 0u;
  if (gid < CLG_NATOMS) {
    float dgx = (float)sqrt((double)cell[0] * cell[0] + (double)cell[3] * cell[3] +
                            (double)cell[6] * cell[6]);
    float dgy = (float)sqrt((double)cell[1] * cell[1] + (double)cell[4] * cell[4] +
                            (double)cell[7] * cell[7]);
    float dgz = (float)sqrt((double)cell[2] * cell[2] + (double)cell[5] * cell[5] +
                            (double)cell[8] * cell[8]);
    float cix = 8.0f / dgx, ciy = 8.0f / dgy, ciz = 8.0f / dgz;
    if (gid == 0) {
      clg_dg = make_float4(dgx, dgy, dgz, 0.f);
      clg_cinv = make_float4(cix, ciy, ciz, 0.f);
      clg_nalive = 0u;
      for (int k = 0; k < CLG_NSHIFT; ++k)
        clg_sf[k] = make_float4(__fmul_rn((float)clg_shifts[k][0], dgx),
                                __fmul_rn((float)clg_shifts[k][1], dgy),
                                __fmul_rn((float)clg_shifts[k][2], dgz), 0.f);
    }
    double a00 = cell[0], a01 = cell[1], a02 = cell[2];
    double a10 = cell[3], a11 = cell[4], a12 = cell[5];
    double a20 = cell[6], a21 = cell[7], a22 = cell[8];
    double det = a00 * (a11 * a22 - a12 * a21) - a01 * (a10 * a22 - a12 * a20) +
                 a02 * (a10 * a21 - a11 * a20);
    double id = 1.0 / det;
    float inv[3][3];
    inv[0][0] = (float)((a11 * a22 - a12 * a21) * id);
    inv[0][1] = (float)(-(a01 * a22 - a02 * a21) * id);
    inv[0][2] = (float)((a01 * a12 - a02 * a11) * id);
    inv[1][0] = (float)(-(a10 * a22 - a12 * a20) * id);
    inv[1][1] = (float)((a00 * a22 - a02 * a20) * id);
    inv[1][2] = (float)(-(a00 * a12 - a02 * a10) * id);
    inv[2][0] = (float)((a10 * a21 - a11 * a20) * id);
    inv[2][1] = (float)(-(a00 * a21 - a01 * a20) * id);
    inv[2][2] = (float)((a00 * a11 - a01 * a10) * id);

    float x = coords[3 * gid], y = coords[3 * gid + 1], z = coords[3 * gid + 2];
    float fr[3], w[3];
#pragma unroll
    for (int c = 0; c < 3; ++c) {
      float f = __fadd_rn(__fadd_rn(__fmul_rn(x, inv[0][c]), __fmul_rn(y, inv[1][c])),
                          __fmul_rn(z, inv[2][c]));
      fr[c] = __fsub_rn(f, floorf(f));
    }
#pragma unroll
    for (int c = 0; c < 3; ++c) {
      w[c] = __fadd_rn(__fadd_rn(__fmul_rn(fr[0], cell[0 * 3 + c]),
                                 __fmul_rn(fr[1], cell[1 * 3 + c])),
                       __fmul_rn(fr[2], cell[2 * 3 + c]));
    }
    clg_pp[gid] = make_float4(w[0], w[1], w[2], 0.0f);
    int cx = min(7, (int)(w[0] * cix));
    int cy = min(7, (int)(w[1] * ciy));
    int cz = min(7, (int)(w[2] * ciz));
    clg_cid[gid] = (cz * 8 + cy) * 8 + cx;  // x fastest -> contiguous x-runs
  }
  grid.sync();

  // ---- P1: block 0 only: LDS hist from cid + exclusive scan ---------------
  if (blockIdx.x == 0) {
    shm.h[tid] = 0u;  // NTHR == NCELL == 512
    __syncthreads();
    for (int r = tid; r < CLG_NATOMS; r += CLG_NTHR) atomicAdd(&shm.h[clg_cid[r]], 1u);
    __syncthreads();
    unsigned v = shm.h[tid];
    unsigned acc = v;
    for (int off = 1; off < CLG_NCELL; off <<= 1) {
      unsigned a = (tid >= off) ? shm.h[tid - off] : 0u;
      __syncthreads();
      acc += a;
      shm.h[tid] = acc;
      __syncthreads();
    }
    clg_cstart[tid] = acc - v;
    clg_cfill[tid] = acc - v;
    if (tid == CLG_NCELL - 1) clg_cstart[CLG_NCELL] = acc;
  }
  grid.sync();

  // ---- P2: scatter (bin-sort) + alive-row list ----------------------------
  // (intra-cell order and alist order nondeterministic; both output-invariant)
  if (gid < CLG_NATOMS) {
    float4 p = clg_pp[gid];
    unsigned pos = atomicAdd(&clg_cfill[clg_cid[gid]], 1u);
    float4 ps = p;
    ps.w = __int_as_float(gid);
    clg_sorted[pos] = ps;

    float4 dg = clg_dg;
    unsigned rows[CLG_NSHIFT];
    int m = 0;
    rows[m++] = (unsigned)gid;  // k = 0 always alive
#pragma unroll
    for (int k = 1; k < CLG_NSHIFT; ++k) {
      if (clg_alive_f(p.x, p.y, p.z, clg_shifts[k][0], clg_shifts[k][1],
                      clg_shifts[k][2], dg.x, dg.y, dg.z))
        rows[m++] = (unsigned)((k << 13) + gid);
    }
    unsigned base = atomicAdd(&clg_nalive, (unsigned)m);
    for (int q = 0; q < m; ++q) clg_alist[base + q] = rows[q];
  }
  grid.sync();

  // ---- P3: count: persistent waves over ALIVE rows; LDS bitmask ->
  // sorted compact j-list + count. Skip test is wave-uniform (round-14 lesson).
  {
    unsigned na = clg_nalive;
    float4 cinv = clg_cinv;
    unsigned* lm = (unsigned*)shm.smask[wslot];

    for (unsigned w = blockIdx.x * 8 + wslot; w < na; w += CLG_NWAVES) {
      unsigned row = clg_alist[w];
      int k = row >> 13, i = row & (CLG_NATOMS - 1);
      float4 sc = clg_sf[k];
      float4 pi = clg_pp[i];
      shm.smask[wslot][lane] = make_uint4(0u, 0u, 0u, 0u);

      int xlo, xhi, ylo, yhi, zlo, zhi;
      clg_crange(__fadd_rn(pi.x, sc.x), cinv.x, xlo, xhi);
      clg_crange(__fadd_rn(pi.y, sc.y), cinv.y, ylo, yhi);
      clg_crange(__fadd_rn(pi.z, sc.z), cinv.z, zlo, zhi);

      for (int cz = zlo; cz <= zhi; ++cz) {
        for (int cy = ylo; cy <= yhi; ++cy) {
          int idb = (cz * 8 + cy) * 8;
          unsigned b = clg_cstart[idb + xlo], e = clg_cstart[idb + xhi + 1];
          for (unsigned t = b + lane; t < e; t += 64) {
            float4 pj = clg_sorted[t];
            int j = __float_as_int(pj.w);
            float dx = __fadd_rn(__fsub_rn(pi.x, pj.x), sc.x);
            float dy = __fadd_rn(__fsub_rn(pi.y, pj.y), sc.y);
            float dz = __fadd_rn(__fsub_rn(pi.z, pj.z), sc.z);
            float d2 = __fadd_rn(__fadd_rn(__fmul_rn(dx, dx), __fmul_rn(dy, dy)),
                                 __fmul_rn(dz, dz));
            bool ok = (d2 <= CLG_C2) && (k != 0 || i < j);
            if (ok) atomicOr(&lm[(unsigned)j >> 5], 1u << (j & 31));
          }
        }
      }
      __threadfence_block();  // drain LDS atomics; all lanes reconverged

      const unsigned long long* mrow = (const unsigned long long*)lm;
      unsigned long long m0 = mrow[lane];       // j in [64*lane, 64*lane+64)
      unsigned long long m1 = mrow[64 + lane];  // j in [4096+64*lane, ...)
      if (__ballot((m0 | m1) != 0ull) == 0ull) continue;  // wave-uniform skip

      unsigned c0 = (unsigned)__popcll(m0), c1 = (unsigned)__popcll(m1);
      unsigned s0 = clg_iscan(c0, lane);
      unsigned T0 = __shfl(s0, 63);
      unsigned e0 = s0 - c0;
      unsigned s1 = clg_iscan(c1, lane);
      unsigned T1 = __shfl(s1, 63);
      unsigned e1 = T0 + s1 - c1;

      size_t jb = (size_t)row * CLG_CAP;
      unsigned p = e0;
      unsigned long long m = m0;
      while (m) {
        int b = __ffsll((long long)m) - 1;
        m &= m - 1;
        if (p < CLG_CAP) clg_jbuf[jb + p] = (lane << 6) + b;
        ++p;
      }
      p = e1;
      m = m1;
      while (m) {
        int b = __ffsll((long long)m) - 1;
        m &= m - 1;
        if (p < CLG_CAP) clg_jbuf[jb + p] = ((64 + lane) << 6) + b;
        ++p;
      }
      if (lane == 0) clg_cnt[row] = min(T0 + T1, (unsigned)CLG_CAP);
    }
  }
  grid.sync();

  // ---- P4: tile scans: first 112 blocks, 1024 rows each, 2 elems/thread ---
  if (blockIdx.x < CLG_NTILE) {
    int base = blockIdx.x * 1024;
    unsigned v0 = clg_cnt[base + 2 * tid], v1 = clg_cnt[base + 2 * tid + 1];
    unsigned ps = v0 + v1;
    shm.sd[tid] = ps;
    __syncthreads();
    unsigned acc = ps;
    for (int off = 1; off < CLG_NTHR; off <<= 1) {
      unsigned a = (tid >= off) ? shm.sd[tid - off] : 0u;
      __syncthreads();
      acc += a;
      shm.sd[tid] = acc;
      __syncthreads();
    }
    unsigned pb = acc - ps;  // exclusive pair base
    clg_off[base + 2 * tid] = pb;
    clg_off[base + 2 * tid + 1] = pb + v0;
    if (tid == CLG_NTHR - 1) clg_tot[blockIdx.x] = acc;
  }
  grid.sync();

  // ---- P5: emit: persistent waves over alive rows; inline tile-base reduce
  {
    unsigned na = clg_nalive;
    for (unsigned w = blockIdx.x * 8 + wslot; w < na; w += CLG_NWAVES) {
      unsigned row = clg_alist[w];
      unsigned c = clg_cnt[row];  // wave-uniform
      if (c == 0) continue;
      int tile = row >> 10;
      unsigned v = 0;
      if (lane < tile) v = clg_tot[lane];
      if (64 + lane < tile) v += clg_tot[64 + lane];
#pragma unroll
      for (int off = 32; off; off >>= 1) v += __shfl_down(v, off);
      unsigned tbase = __shfl(v, 0);

      unsigned off0 = clg_off[row] + tbase;
      int k = row >> 13, i = row & (CLG_NATOMS - 1);
      int sx = clg_shifts[k][0], sy = clg_shifts[k][1], sz = clg_shifts[k][2];
      size_t jb = (size_t)row * CLG_CAP;
      for (unsigned q = lane; q < c; q += 64) {
        unsigned p = off0 + q;
        if (p < (unsigned)P) {
          out[p] = i;
          out[P + p] = clg_jbuf[jb + q];
          unsigned sp = 2u * (unsigned)P + 3u * p;
          out[sp] = sx;
          out[sp + 1] = sy;
          out[sp + 2] = sz;
        }
      }
    }
  }
}

extern "C" void kernel_launch(void* const* d_in, const int* in_sizes, int n_in,
                              void* d_out, int out_size, void* d_ws, size_t ws_size,
                              hipStream_t stream) {
  const float* coords = (const float*)d_in[1];  // (1, N, 3) f32
  const float* cell = (const float*)d_in[2];    // (3, 3) f32
  int* outp = (int*)d_out;
  int P = out_size / 5;

  void* args[] = {(void*)&coords, (void*)&cell, (void*)&outp, (void*)&P};
  hipLaunchCooperativeKernel((const void*)clg_fused, dim3(CLG_NBLK), dim3(CLG_NTHR),
                             args, 0, stream);
}

// Round 17
// 117.686 us; speedup vs baseline: 1.6461x; 1.6461x over previous
//
#include <hip/hip_runtime.h>

#define CLH_NATOMS 8192
#define CLH_NSHIFT 14
#define CLH_NROWS (CLH_NSHIFT * CLH_NATOMS)  // 114688 rows = (k, i)
#define CLH_NCELL 512                        // 8x8x8 spatial bins
#define CLH_CAP 128                          // max hits per row (k=0 max ~90)
#define CLH_TROWS 128                        // rows per L3 block (tile)
#define CLH_NTILE (CLH_NROWS / CLH_TROWS)    // 896 tiles/blocks
#define CLH_C2 ((float)(5.2 * 5.2))          // f32 compare (JAX weak promotion)
#define CLH_R 5.35f                          // candidate interval half-width

__device__ const int clh_shifts[CLH_NSHIFT][3] = {
    {0, 0, 0},
    {-1, 0, 0}, {-1, -1, 0}, {0, -1, 0}, {1, -1, 0},
    {-1, 1, -1}, {0, 1, -1}, {1, 1, -1}, {-1, 0, -1},
    {0, 0, -1}, {1, 0, -1}, {-1, -1, -1}, {0, -1, -1}, {1, -1, -1}};

// Module-owned scratch (d_ws unused). Everything read is rewritten each call.
__device__ float4 clh_pp[CLH_NATOMS];      // wrapped coords
__device__ int clh_cid[CLH_NATOMS];        // cell id per atom
__device__ float4 clh_sorted[CLH_NATOMS];  // bin-sorted coords, .w = original i
__device__ unsigned clh_cstart[CLH_NCELL + 1];
__device__ unsigned clh_cfill[CLH_NCELL];
__device__ unsigned clh_flag;                       // L2 producer flag
__device__ unsigned long long clh_tstat[CLH_NTILE]; // lookback: (1<<32)|aggregate
__device__ int clh_jbuf[(size_t)CLH_NROWS * CLH_CAP];  // per-row sorted hit j's
__device__ float4 clh_dg;                  // cell diagonal
__device__ float4 clh_cinv;                // 8/diag per axis
__device__ float4 clh_sf[CLH_NSHIFT];      // s * diag (f32, __fmul_rn)

// Slab prune: d2<=c2 forces shifted atom i into a cutoff-wide boundary slab.
__device__ __forceinline__ bool clh_alive(float xi, float yi, float zi, int sx, int sy,
                                          int sz, float dgx, float dgy, float dgz) {
  bool a = true;
  if (sx < 0) a = a && (xi >= dgx - 5.3f); else if (sx > 0) a = a && (xi <= 5.3f);
  if (sy < 0) a = a && (yi >= dgy - 5.3f); else if (sy > 0) a = a && (yi <= 5.3f);
  if (sz < 0) a = a && (zi >= dgz - 5.3f); else if (sz > 0) a = a && (zi <= 5.3f);
  return a;
}

// Candidate cell range on one axis (monotone-rounding safe, 0.14 slack).
__device__ __forceinline__ void clh_crange(float t, float ci, int& lo, int& hi) {
  lo = max(0, (int)(fmaxf(t - CLH_R, 0.f) * ci));
  hi = min(7, (int)(fmaxf(t + CLH_R, 0.f) * ci));
}

__device__ __forceinline__ unsigned clh_iscan(unsigned v, int lane) {
  for (int off = 1; off < 64; off <<= 1) {
    unsigned t = __shfl_up(v, off);
    if (lane >= off) v += t;
  }
  return v;
}

// --- L1: wrap + cell-id; zero lookback state; publish constants -------------
// frac = x @ inv(cell); frac -= floor(frac); w = frac @ cell   (f32 per-op RN)
__global__ __launch_bounds__(256) void clh_wrapbin(const float* __restrict__ coords,
                                                   const float* __restrict__ cell) {
  int i = blockIdx.x * blockDim.x + threadIdx.x;
  if (i >= CLH_NATOMS) return;
  if (i < CLH_NTILE) clh_tstat[i] = 0ull;
  if (i == 0) clh_flag = 0u;

  float dgx = (float)sqrt((double)cell[0] * cell[0] + (double)cell[3] * cell[3] +
                          (double)cell[6] * cell[6]);
  float dgy = (float)sqrt((double)cell[1] * cell[1] + (double)cell[4] * cell[4] +
                          (double)cell[7] * cell[7]);
  float dgz = (float)sqrt((double)cell[2] * cell[2] + (double)cell[5] * cell[5] +
                          (double)cell[8] * cell[8]);
  float cix = 8.0f / dgx, ciy = 8.0f / dgy, ciz = 8.0f / dgz;
  if (i == 0) {
    clh_dg = make_float4(dgx, dgy, dgz, 0.f);
    clh_cinv = make_float4(cix, ciy, ciz, 0.f);
    for (int k = 0; k < CLH_NSHIFT; ++k)
      clh_sf[k] = make_float4(__fmul_rn((float)clh_shifts[k][0], dgx),
                              __fmul_rn((float)clh_shifts[k][1], dgy),
                              __fmul_rn((float)clh_shifts[k][2], dgz), 0.f);
  }

  double a00 = cell[0], a01 = cell[1], a02 = cell[2];
  double a10 = cell[3], a11 = cell[4], a12 = cell[5];
  double a20 = cell[6], a21 = cell[7], a22 = cell[8];
  double det = a00 * (a11 * a22 - a12 * a21) - a01 * (a10 * a22 - a12 * a20) +
               a02 * (a10 * a21 - a11 * a20);
  double id = 1.0 / det;
  float inv[3][3];
  inv[0][0] = (float)((a11 * a22 - a12 * a21) * id);
  inv[0][1] = (float)(-(a01 * a22 - a02 * a21) * id);
  inv[0][2] = (float)((a01 * a12 - a02 * a11) * id);
  inv[1][0] = (float)(-(a10 * a22 - a12 * a20) * id);
  inv[1][1] = (float)((a00 * a22 - a02 * a20) * id);
  inv[1][2] = (float)(-(a00 * a12 - a02 * a10) * id);
  inv[2][0] = (float)((a10 * a21 - a11 * a20) * id);
  inv[2][1] = (float)(-(a00 * a21 - a01 * a20) * id);
  inv[2][2] = (float)((a00 * a11 - a01 * a10) * id);

  float x = coords[3 * i], y = coords[3 * i + 1], z = coords[3 * i + 2];
  float fr[3], w[3];
#pragma unroll
  for (int c = 0; c < 3; ++c) {
    float f = __fadd_rn(__fadd_rn(__fmul_rn(x, inv[0][c]), __fmul_rn(y, inv[1][c])),
                        __fmul_rn(z, inv[2][c]));
    fr[c] = __fsub_rn(f, floorf(f));
  }
#pragma unroll
  for (int c = 0; c < 3; ++c) {
    w[c] = __fadd_rn(
        __fadd_rn(__fmul_rn(fr[0], cell[0 * 3 + c]), __fmul_rn(fr[1], cell[1 * 3 + c])),
        __fmul_rn(fr[2], cell[2 * 3 + c]));
  }
  clh_pp[i] = make_float4(w[0], w[1], w[2], 0.0f);
  int cx = min(7, (int)(w[0] * cix));
  int cy = min(7, (int)(w[1] * ciy));
  int cz = min(7, (int)(w[2] * ciz));
  clh_cid[i] = (cz * 8 + cy) * 8 + cx;  // x fastest -> contiguous x-runs
}

// --- L2: block 0 builds hist+scan (cstart/cfill), sets flag; 15 other blocks
// spin on the flag (single lane), then all 16 blocks scatter 512 atoms each.
// Replay-safe: L1 re-zeroes clh_flag before this kernel every graph replay. --
__global__ __launch_bounds__(512) void clh_scatterfused() {
  __shared__ unsigned h[CLH_NCELL];
  int tid = threadIdx.x;
  if (blockIdx.x == 0) {
    h[tid] = 0u;
    __syncthreads();
    for (int r = tid; r < CLH_NATOMS; r += 512) atomicAdd(&h[clh_cid[r]], 1u);
    __syncthreads();
    unsigned v = h[tid];
    unsigned acc = v;
    for (int off = 1; off < CLH_NCELL; off <<= 1) {
      unsigned a = (tid >= off) ? h[tid - off] : 0u;
      __syncthreads();
      acc += a;
      h[tid] = acc;
      __syncthreads();
    }
    clh_cstart[tid] = acc - v;
    atomicExch(&clh_cfill[tid], acc - v);
    if (tid == CLH_NCELL - 1) clh_cstart[CLH_NCELL] = acc;
    __threadfence();
    __syncthreads();
    if (tid == 0) atomicExch(&clh_flag, 1u);
  } else {
    if (tid == 0) {
      while (atomicAdd(&clh_flag, 0u) == 0u) __builtin_amdgcn_s_sleep(8);
    }
    __syncthreads();
    __threadfence();
  }
  // scatter (intra-cell order nondeterministic; output-invariant: hits are
  // keyed by original atom index j, not storage position)
  int i = blockIdx.x * 512 + tid;
  float4 p = clh_pp[i];
  unsigned pos = atomicAdd(&clh_cfill[clh_cid[i]], 1u);
  p.w = __int_as_float(i);
  clh_sorted[pos] = p;
}

// --- L3: mega: per 128-row tile: count -> LDS block scan -> publish aggregate
// -> lookback-sum predecessors -> emit. No grid barrier; only predecessor
// waits (DAG, all 896 blocks co-resident at 28 waves/CU). ---------------------
__global__ __launch_bounds__(512) void clh_mega(int* __restrict__ out, int P) {
  __shared__ uint4 smask[8][64];     // 1KB mask per wave
  __shared__ unsigned scnt[CLH_TROWS];
  __shared__ unsigned soff[CLH_TROWS];
  __shared__ unsigned sbase;
  int tid = threadIdx.x;
  int wslot = tid >> 6;
  int lane = tid & 63;
  unsigned* lm = (unsigned*)smask[wslot];

  float4 dg = clh_dg;
  float4 cinv = clh_cinv;

  // ---- count: wave w handles rows [tile*128 + w*16, +16) -------------------
  for (int r = 0; r < CLH_TROWS / 8; ++r) {
    int local = wslot * (CLH_TROWS / 8) + r;
    int row = blockIdx.x * CLH_TROWS + local;
    int k = row >> 13, i = row & (CLH_NATOMS - 1);
    int sx = clh_shifts[k][0], sy = clh_shifts[k][1], sz = clh_shifts[k][2];
    float4 pi = clh_pp[i];  // same addr all lanes -> broadcast; branch uniform
    if (k != 0 && !clh_alive(pi.x, pi.y, pi.z, sx, sy, sz, dg.x, dg.y, dg.z)) {
      if (lane == 0) scnt[local] = 0u;
      continue;
    }
    float4 sc = clh_sf[k];
    smask[wslot][lane] = make_uint4(0u, 0u, 0u, 0u);

    int xlo, xhi, ylo, yhi, zlo, zhi;
    clh_crange(__fadd_rn(pi.x, sc.x), cinv.x, xlo, xhi);
    clh_crange(__fadd_rn(pi.y, sc.y), cinv.y, ylo, yhi);
    clh_crange(__fadd_rn(pi.z, sc.z), cinv.z, zlo, zhi);

    for (int cz = zlo; cz <= zhi; ++cz) {
      for (int cy = ylo; cy <= yhi; ++cy) {
        int idb = (cz * 8 + cy) * 8;
        unsigned b = clh_cstart[idb + xlo], e = clh_cstart[idb + xhi + 1];
        for (unsigned t = b + lane; t < e; t += 64) {
          float4 pj = clh_sorted[t];
          int j = __float_as_int(pj.w);
          float dx = __fadd_rn(__fsub_rn(pi.x, pj.x), sc.x);
          float dy = __fadd_rn(__fsub_rn(pi.y, pj.y), sc.y);
          float dz = __fadd_rn(__fsub_rn(pi.z, pj.z), sc.z);
          float d2 = __fadd_rn(__fadd_rn(__fmul_rn(dx, dx), __fmul_rn(dy, dy)),
                               __fmul_rn(dz, dz));
          bool ok = (d2 <= CLH_C2) && (k != 0 || i < j);
          if (ok) atomicOr(&lm[(unsigned)j >> 5], 1u << (j & 31));
        }
      }
    }
    __threadfence_block();  // drain LDS atomics; lanes reconverged here

    const unsigned long long* mrow = (const unsigned long long*)lm;
    unsigned long long m0 = mrow[lane];
    unsigned long long m1 = mrow[64 + lane];
    if (__ballot((m0 | m1) != 0ull) == 0ull) {  // wave-uniform empty skip
      if (lane == 0) scnt[local] = 0u;
      continue;
    }
    unsigned c0 = (unsigned)__popcll(m0), c1 = (unsigned)__popcll(m1);
    unsigned s0 = clh_iscan(c0, lane);
    unsigned T0 = __shfl(s0, 63);
    unsigned e0 = s0 - c0;
    unsigned s1 = clh_iscan(c1, lane);
    unsigned T1 = __shfl(s1, 63);
    unsigned e1 = T0 + s1 - c1;

    size_t jb = (size_t)row * CLH_CAP;
    unsigned p = e0;
    unsigned long long m = m0;
    while (m) {
      int b = __ffsll((long long)m) - 1;
      m &= m - 1;
      if (p < CLH_CAP) clh_jbuf[jb + p] = (lane << 6) + b;
      ++p;
    }
    p = e1;
    m = m1;
    while (m) {
      int b = __ffsll((long long)m) - 1;
      m &= m - 1;
      if (p < CLH_CAP) clh_jbuf[jb + p] = ((64 + lane) << 6) + b;
      ++p;
    }
    if (lane == 0) scnt[local] = min(T0 + T1, (unsigned)CLH_CAP);
  }
  __syncthreads();

  // ---- block scan of 128 row counts (inclusive into soff) ------------------
  unsigned v = (tid < CLH_TROWS) ? scnt[tid] : 0u;
  if (tid < CLH_TROWS) soff[tid] = v;
  __syncthreads();
  unsigned acc = v;
  for (int off = 1; off < CLH_TROWS; off <<= 1) {
    unsigned a = (tid >= off && tid < CLH_TROWS) ? soff[tid - off] : 0u;
    __syncthreads();
    if (tid < CLH_TROWS) {
      acc += a;
      soff[tid] = acc;
    }
    __syncthreads();
  }
  // ---- publish aggregate, lookback-sum predecessors ------------------------
  if (tid == 0)
    atomicExch(&clh_tstat[blockIdx.x],
               (1ull << 32) | (unsigned long long)soff[CLH_TROWS - 1]);
  if (tid < 64) {
    unsigned sum = 0;
    for (int t = tid; t < (int)blockIdx.x; t += 64) {
      unsigned long long vv;
      do {
        vv = atomicAdd(&clh_tstat[t], 0ull);
        if (!(vv >> 32)) __builtin_amdgcn_s_sleep(2);
      } while (!(vv >> 32));
      sum += (unsigned)vv;
    }
#pragma unroll
    for (int off = 32; off; off >>= 1) sum += __shfl_down(sum, off);
    if (tid == 0) sbase = sum;
  }
  __syncthreads();

  // ---- emit: wave w writes its 16 rows' pairs coalesced --------------------
  unsigned tbase = sbase;
  for (int r = 0; r < CLH_TROWS / 8; ++r) {
    int local = wslot * (CLH_TROWS / 8) + r;
    unsigned c = scnt[local];  // LDS broadcast, wave-uniform
    if (c == 0) continue;
    int row = blockIdx.x * CLH_TROWS + local;
    int k = row >> 13, i = row & (CLH_NATOMS - 1);
    int sx = clh_shifts[k][0], sy = clh_shifts[k][1], sz = clh_shifts[k][2];
    unsigned off0 = tbase + soff[local] - c;  // exclusive
    size_t jb = (size_t)row * CLH_CAP;
    for (unsigned q = lane; q < c; q += 64) {
      unsigned p = off0 + q;
      if (p < (unsigned)P) {
        out[p] = i;
        out[P + p] = clh_jbuf[jb + q];
        unsigned sp = 2u * (unsigned)P + 3u * p;
        out[sp] = sx;
        out[sp + 1] = sy;
        out[sp + 2] = sz;
      }
    }
  }
}

extern "C" void kernel_launch(void* const* d_in, const int* in_sizes, int n_in,
                              void* d_out, int out_size, void* d_ws, size_t ws_size,
                              hipStream_t stream) {
  const float* coords = (const float*)d_in[1];  // (1, N, 3) f32
  const float* cell = (const float*)d_in[2];    // (3, 3) f32
  int P = out_size / 5;

  clh_wrapbin<<<CLH_NATOMS / 256, 256, 0, stream>>>(coords, cell);
  clh_scatterfused<<<16, 512, 0, stream>>>();
  clh_mega<<<CLH_NTILE, 512, 0, stream>>>((int*)d_out, P);
}

// Round 18
// 81.368 us; speedup vs baseline: 2.3808x; 1.4464x over previous
//
#include <hip/hip_runtime.h>

#define CLI_NATOMS 8192
#define CLI_NSHIFT 14
#define CLI_NROWS (CLI_NSHIFT * CLI_NATOMS)  // 114688 rows = (k, i)
#define CLI_NTILE 112                        // scan tiles of 1024 rows
#define CLI_NCELL 512                        // 8x8x8 spatial bins
#define CLI_CAP 128                          // max hits per row (k=0 max ~90)
#define CLI_PWAVES 8192                      // persistent waves (1024 blk x 8)
#define CLI_C2 ((float)(5.2 * 5.2))          // f32 compare (JAX weak promotion)
#define CLI_R 5.35f                          // candidate interval half-width

__device__ const int cli_shifts[CLI_NSHIFT][3] = {
    {0, 0, 0},
    {-1, 0, 0}, {-1, -1, 0}, {0, -1, 0}, {1, -1, 0},
    {-1, 1, -1}, {0, 1, -1}, {1, 1, -1}, {-1, 0, -1},
    {0, 0, -1}, {1, 0, -1}, {-1, -1, -1}, {0, -1, -1}, {1, -1, -1}};

// Module-owned scratch (d_ws unused). Everything read is rewritten each call.
__device__ float4 cli_pp[CLI_NATOMS];      // wrapped coords
__device__ int cli_cid[CLI_NATOMS];        // cell id per atom
__device__ float4 cli_sorted[CLI_NATOMS];  // bin-sorted coords, .w = original i
__device__ unsigned cli_cstart[CLI_NCELL + 1];
__device__ unsigned cli_cfill[CLI_NCELL];
__device__ unsigned cli_flag;              // L2 producer flag
__device__ unsigned cli_nalive;            // alive-row count
__device__ unsigned cli_alist[CLI_NROWS];  // alive row ids (k<<13 | i)
__device__ unsigned long long cli_tstat[CLI_NTILE];  // lookback (1<<32)|aggregate
__device__ int cli_jbuf[(size_t)CLI_NROWS * CLI_CAP];  // per-row sorted hit j's
__device__ unsigned cli_cnt[CLI_NROWS];
__device__ float4 cli_dg;                  // cell diagonal
__device__ float4 cli_cinv;                // 8/diag per axis
__device__ float4 cli_sf[CLI_NSHIFT];      // s * diag (f32, __fmul_rn)

// Slab prune: d2<=c2 forces shifted atom i into a cutoff-wide boundary slab.
__device__ __forceinline__ bool cli_alive_f(float xi, float yi, float zi, int sx,
                                            int sy, int sz, float dgx, float dgy,
                                            float dgz) {
  bool a = true;
  if (sx < 0) a = a && (xi >= dgx - 5.3f); else if (sx > 0) a = a && (xi <= 5.3f);
  if (sy < 0) a = a && (yi >= dgy - 5.3f); else if (sy > 0) a = a && (yi <= 5.3f);
  if (sz < 0) a = a && (zi >= dgz - 5.3f); else if (sz > 0) a = a && (zi <= 5.3f);
  return a;
}

// Candidate cell range on one axis (monotone-rounding safe, 0.14 slack).
__device__ __forceinline__ void cli_crange(float t, float ci, int& lo, int& hi) {
  lo = max(0, (int)(fmaxf(t - CLI_R, 0.f) * ci));
  hi = min(7, (int)(fmaxf(t + CLI_R, 0.f) * ci));
}

__device__ __forceinline__ unsigned cli_iscan(unsigned v, int lane) {
  for (int off = 1; off < 64; off <<= 1) {
    unsigned t = __shfl_up(v, off);
    if (lane >= off) v += t;
  }
  return v;
}

// --- L1: wrap + cell-id; zero cnt/tstat/flag/nalive; publish constants ------
// frac = x @ inv(cell); frac -= floor(frac); w = frac @ cell   (f32 per-op RN)
__global__ __launch_bounds__(256) void cli_wrapbin(const float* __restrict__ coords,
                                                   const float* __restrict__ cell) {
  int i = blockIdx.x * blockDim.x + threadIdx.x;
  if (i >= CLI_NATOMS) return;
  if (i < CLI_NTILE) cli_tstat[i] = 0ull;
  if (i == 0) {
    cli_flag = 0u;
    cli_nalive = 0u;
  }
#pragma unroll
  for (int k = 0; k < CLI_NSHIFT; ++k) cli_cnt[(k << 13) + i] = 0u;  // coalesced

  float dgx = (float)sqrt((double)cell[0] * cell[0] + (double)cell[3] * cell[3] +
                          (double)cell[6] * cell[6]);
  float dgy = (float)sqrt((double)cell[1] * cell[1] + (double)cell[4] * cell[4] +
                          (double)cell[7] * cell[7]);
  float dgz = (float)sqrt((double)cell[2] * cell[2] + (double)cell[5] * cell[5] +
                          (double)cell[8] * cell[8]);
  float cix = 8.0f / dgx, ciy = 8.0f / dgy, ciz = 8.0f / dgz;
  if (i == 0) {
    cli_dg = make_float4(dgx, dgy, dgz, 0.f);
    cli_cinv = make_float4(cix, ciy, ciz, 0.f);
    for (int k = 0; k < CLI_NSHIFT; ++k)
      cli_sf[k] = make_float4(__fmul_rn((float)cli_shifts[k][0], dgx),
                              __fmul_rn((float)cli_shifts[k][1], dgy),
                              __fmul_rn((float)cli_shifts[k][2], dgz), 0.f);
  }

  double a00 = cell[0], a01 = cell[1], a02 = cell[2];
  double a10 = cell[3], a11 = cell[4], a12 = cell[5];
  double a20 = cell[6], a21 = cell[7], a22 = cell[8];
  double det = a00 * (a11 * a22 - a12 * a21) - a01 * (a10 * a22 - a12 * a20) +
               a02 * (a10 * a21 - a11 * a20);
  double id = 1.0 / det;
  float inv[3][3];
  inv[0][0] = (float)((a11 * a22 - a12 * a21) * id);
  inv[0][1] = (float)(-(a01 * a22 - a02 * a21) * id);
  inv[0][2] = (float)((a01 * a12 - a02 * a11) * id);
  inv[1][0] = (float)(-(a10 * a22 - a12 * a20) * id);
  inv[1][1] = (float)((a00 * a22 - a02 * a20) * id);
  inv[1][2] = (float)(-(a00 * a12 - a02 * a10) * id);
  inv[2][0] = (float)((a10 * a21 - a11 * a20) * id);
  inv[2][1] = (float)(-(a00 * a21 - a01 * a20) * id);
  inv[2][2] = (float)((a00 * a11 - a01 * a10) * id);

  float x = coords[3 * i], y = coords[3 * i + 1], z = coords[3 * i + 2];
  float fr[3], w[3];
#pragma unroll
  for (int c = 0; c < 3; ++c) {
    float f = __fadd_rn(__fadd_rn(__fmul_rn(x, inv[0][c]), __fmul_rn(y, inv[1][c])),
                        __fmul_rn(z, inv[2][c]));
    fr[c] = __fsub_rn(f, floorf(f));
  }
#pragma unroll
  for (int c = 0; c < 3; ++c) {
    w[c] = __fadd_rn(
        __fadd_rn(__fmul_rn(fr[0], cell[0 * 3 + c]), __fmul_rn(fr[1], cell[1 * 3 + c])),
        __fmul_rn(fr[2], cell[2 * 3 + c]));
  }
  cli_pp[i] = make_float4(w[0], w[1], w[2], 0.0f);
  int cx = min(7, (int)(w[0] * cix));
  int cy = min(7, (int)(w[1] * ciy));
  int cz = min(7, (int)(w[2] * ciz));
  cli_cid[i] = (cz * 8 + cy) * 8 + cx;  // x fastest -> contiguous x-runs
}

// --- L2: block 0 builds hist+scan (cstart/cfill), sets flag; 15 other blocks
// spin (single lane) then all scatter 512 atoms each + build alive-row list.
// Replay-safe: L1 re-zeroes flag/nalive before this kernel each replay. ------
__global__ __launch_bounds__(512) void cli_scatterfused() {
  __shared__ unsigned h[CLI_NCELL];
  int tid = threadIdx.x;
  if (blockIdx.x == 0) {
    h[tid] = 0u;
    __syncthreads();
    for (int r = tid; r < CLI_NATOMS; r += 512) atomicAdd(&h[cli_cid[r]], 1u);
    __syncthreads();
    unsigned v = h[tid];
    unsigned acc = v;
    for (int off = 1; off < CLI_NCELL; off <<= 1) {
      unsigned a = (tid >= off) ? h[tid - off] : 0u;
      __syncthreads();
      acc += a;
      h[tid] = acc;
      __syncthreads();
    }
    cli_cstart[tid] = acc - v;
    atomicExch(&cli_cfill[tid], acc - v);
    if (tid == CLI_NCELL - 1) cli_cstart[CLI_NCELL] = acc;
    __threadfence();
    __syncthreads();
    if (tid == 0) atomicExch(&cli_flag, 1u);
  } else {
    if (tid == 0) {
      while (atomicAdd(&cli_flag, 0u) == 0u) __builtin_amdgcn_s_sleep(8);
    }
    __syncthreads();
    __threadfence();
  }
  // scatter (intra-cell order nondeterministic; output-invariant)
  int i = blockIdx.x * 512 + tid;
  float4 p = cli_pp[i];
  unsigned pos = atomicAdd(&cli_cfill[cli_cid[i]], 1u);
  float4 ps = p;
  ps.w = __int_as_float(i);
  cli_sorted[pos] = ps;

  // alive (k,i) row list (alist order nondeterministic; output-invariant)
  float4 dg = cli_dg;
  unsigned rows[CLI_NSHIFT];
  int m = 0;
  rows[m++] = (unsigned)i;  // k = 0 always alive
#pragma unroll
  for (int k = 1; k < CLI_NSHIFT; ++k) {
    if (cli_alive_f(p.x, p.y, p.z, cli_shifts[k][0], cli_shifts[k][1],
                    cli_shifts[k][2], dg.x, dg.y, dg.z))
      rows[m++] = (unsigned)((k << 13) + i);
  }
  unsigned base = atomicAdd(&cli_nalive, (unsigned)m);
  for (int q = 0; q < m; ++q) cli_alist[base + q] = rows[q];
}

// --- L3: count: persistent waves over ALIVE rows (balanced); per row:
// cell-list candidates -> LDS bitmask -> sorted compact j-list + count.
// Skip test is wave-uniform from the reconverged mask (round-14 lesson). -----
__global__ __launch_bounds__(512) void cli_count() {
  __shared__ uint4 smask[8][64];  // 1KB mask per wave
  int wslot = threadIdx.x >> 6;
  int lane = threadIdx.x & 63;
  unsigned* lm = (unsigned*)smask[wslot];
  unsigned na = cli_nalive;
  float4 cinv = cli_cinv;

  for (unsigned w = blockIdx.x * 8 + wslot; w < na; w += CLI_PWAVES) {
    unsigned row = cli_alist[w];
    int k = row >> 13, i = row & (CLI_NATOMS - 1);
    float4 sc = cli_sf[k];
    float4 pi = cli_pp[i];
    smask[wslot][lane] = make_uint4(0u, 0u, 0u, 0u);

    int xlo, xhi, ylo, yhi, zlo, zhi;
    cli_crange(__fadd_rn(pi.x, sc.x), cinv.x, xlo, xhi);
    cli_crange(__fadd_rn(pi.y, sc.y), cinv.y, ylo, yhi);
    cli_crange(__fadd_rn(pi.z, sc.z), cinv.z, zlo, zhi);

    for (int cz = zlo; cz <= zhi; ++cz) {
      for (int cy = ylo; cy <= yhi; ++cy) {
        int idb = (cz * 8 + cy) * 8;
        unsigned b = cli_cstart[idb + xlo], e = cli_cstart[idb + xhi + 1];
        for (unsigned t = b + lane; t < e; t += 64) {
          float4 pj = cli_sorted[t];
          int j = __float_as_int(pj.w);
          float dx = __fadd_rn(__fsub_rn(pi.x, pj.x), sc.x);
          float dy = __fadd_rn(__fsub_rn(pi.y, pj.y), sc.y);
          float dz = __fadd_rn(__fsub_rn(pi.z, pj.z), sc.z);
          float d2 = __fadd_rn(__fadd_rn(__fmul_rn(dx, dx), __fmul_rn(dy, dy)),
                               __fmul_rn(dz, dz));
          bool ok = (d2 <= CLI_C2) && (k != 0 || i < j);
          if (ok) atomicOr(&lm[(unsigned)j >> 5], 1u << (j & 31));
        }
      }
    }
    __threadfence_block();  // drain LDS atomics; all lanes reconverged here

    const unsigned long long* mrow = (const unsigned long long*)lm;
    unsigned long long m0 = mrow[lane];       // j in [64*lane, 64*lane+64)
    unsigned long long m1 = mrow[64 + lane];  // j in [4096+64*lane, ...)
    if (__ballot((m0 | m1) != 0ull) == 0ull) continue;  // wave-uniform skip

    unsigned c0 = (unsigned)__popcll(m0), c1 = (unsigned)__popcll(m1);
    unsigned s0 = cli_iscan(c0, lane);
    unsigned T0 = __shfl(s0, 63);
    unsigned e0 = s0 - c0;
    unsigned s1 = cli_iscan(c1, lane);
    unsigned T1 = __shfl(s1, 63);
    unsigned e1 = T0 + s1 - c1;

    size_t jb = (size_t)row * CLI_CAP;
    unsigned p = e0;
    unsigned long long m = m0;
    while (m) {
      int b = __ffsll((long long)m) - 1;
      m &= m - 1;
      if (p < CLI_CAP) cli_jbuf[jb + p] = (lane << 6) + b;
      ++p;
    }
    p = e1;
    m = m1;
    while (m) {
      int b = __ffsll((long long)m) - 1;
      m &= m - 1;
      if (p < CLI_CAP) cli_jbuf[jb + p] = ((64 + lane) << 6) + b;
      ++p;
    }
    if (lane == 0) cli_cnt[row] = min(T0 + T1, (unsigned)CLI_CAP);
  }
}

// --- L4: scanemit: 112 blocks x 1024; per block: scan its 1024 row counts,
// publish aggregate, lookback-sum predecessors (<=111, all co-resident),
// then 16 waves emit 64 rows each, lanes copying pairs coalesced. ------------
__global__ __launch_bounds__(1024) void cli_scanemit(int* __restrict__ out, int P) {
  __shared__ unsigned scnt[1024];
  __shared__ unsigned soff[1024];
  __shared__ unsigned sbase;
  int tid = threadIdx.x;
  int gid = blockIdx.x * 1024 + tid;

  unsigned v = cli_cnt[gid];
  scnt[tid] = v;
  soff[tid] = v;
  __syncthreads();
  unsigned acc = v;
  for (int off = 1; off < 1024; off <<= 1) {
    unsigned a = (tid >= off) ? soff[tid - off] : 0u;
    __syncthreads();
    acc += a;
    soff[tid] = acc;  // inclusive scan
    __syncthreads();
  }
  if (tid == 1023)
    atomicExch(&cli_tstat[blockIdx.x], (1ull << 32) | (unsigned long long)acc);
  if (tid < 64) {
    unsigned sum = 0;
    for (int t = tid; t < (int)blockIdx.x; t += 64) {
      unsigned long long vv;
      do {
        vv = atomicAdd(&cli_tstat[t], 0ull);
        if (!(vv >> 32)) __builtin_amdgcn_s_sleep(2);
      } while (!(vv >> 32));
      sum += (unsigned)vv;
    }
#pragma unroll
    for (int off = 32; off; off >>= 1) sum += __shfl_down(sum, off);
    if (tid == 0) sbase = sum;
  }
  __syncthreads();

  unsigned tbase = sbase;
  int wslot = tid >> 6;
  int lane = tid & 63;
  for (int local = wslot; local < 1024; local += 16) {
    unsigned c = scnt[local];  // LDS broadcast, wave-uniform
    if (c == 0) continue;
    int row = blockIdx.x * 1024 + local;
    int k = row >> 13, i = row & (CLI_NATOMS - 1);
    int sx = cli_shifts[k][0], sy = cli_shifts[k][1], sz = cli_shifts[k][2];
    unsigned off0 = tbase + soff[local] - c;  // exclusive
    size_t jb = (size_t)row * CLI_CAP;
    for (unsigned q = lane; q < c; q += 64) {
      unsigned p = off0 + q;
      if (p < (unsigned)P) {
        out[p] = i;
        out[P + p] = cli_jbuf[jb + q];
        unsigned sp = 2u * (unsigned)P + 3u * p;
        out[sp] = sx;
        out[sp + 1] = sy;
        out[sp + 2] = sz;
      }
    }
  }
}

extern "C" void kernel_launch(void* const* d_in, const int* in_sizes, int n_in,
                              void* d_out, int out_size, void* d_ws, size_t ws_size,
                              hipStream_t stream) {
  const float* coords = (const float*)d_in[1];  // (1, N, 3) f32
  const float* cell = (const float*)d_in[2];    // (3, 3) f32
  int P = out_size / 5;

  cli_wrapbin<<<CLI_NATOMS / 256, 256, 0, stream>>>(coords, cell);
  cli_scatterfused<<<16, 512, 0, stream>>>();
  cli_count<<<CLI_PWAVES / 8, 512, 0, stream>>>();
  cli_scanemit<<<CLI_NTILE, 1024, 0, stream>>>((int*)d_out, P);
}

// Round 19
// 50.698 us; speedup vs baseline: 3.8210x; 1.6049x over previous
//
#include <hip/hip_runtime.h>

#define CLJ_NATOMS 8192
#define CLJ_NSHIFT 14
#define CLJ_NROWS (CLJ_NSHIFT * CLJ_NATOMS)  // 114688 rows = (k, i)
#define CLJ_NTILE 112                        // scan tiles of 1024 rows
#define CLJ_NCELL 512                        // 8x8x8 spatial bins
#define CLJ_CAP 128                          // max hits per row (k=0 max ~90)
#define CLJ_PWAVES 8192                      // persistent waves (1024 blk x 8)
#define CLJ_C2 ((float)(5.2 * 5.2))          // f32 compare (JAX weak promotion)
#define CLJ_R 5.35f                          // candidate interval half-width

__device__ const int clj_shifts[CLJ_NSHIFT][3] = {
    {0, 0, 0},
    {-1, 0, 0}, {-1, -1, 0}, {0, -1, 0}, {1, -1, 0},
    {-1, 1, -1}, {0, 1, -1}, {1, 1, -1}, {-1, 0, -1},
    {0, 0, -1}, {1, 0, -1}, {-1, -1, -1}, {0, -1, -1}, {1, -1, -1}};

// Module-owned scratch (d_ws unused). Everything read is rewritten each call.
__device__ float4 clj_pp[CLJ_NATOMS];      // wrapped coords
__device__ int clj_cid[CLJ_NATOMS];        // cell id per atom
__device__ float4 clj_sorted[CLJ_NATOMS];  // bin-sorted coords, .w = original i
__device__ unsigned clj_cstart[CLJ_NCELL + 1];
__device__ unsigned clj_cfill[CLJ_NCELL];
__device__ unsigned clj_flag;              // L2 producer flag
__device__ unsigned clj_nalive;            // alive-row count
__device__ unsigned clj_alist[CLJ_NROWS];  // alive row ids (k<<13 | i)
__device__ int clj_jbuf[(size_t)CLJ_NROWS * CLJ_CAP];  // per-row sorted hit j's
__device__ unsigned clj_cnt[CLJ_NROWS];
__device__ unsigned clj_off[CLJ_NROWS];    // exclusive offset WITHIN tile
__device__ unsigned clj_tot[CLJ_NTILE];    // per-tile totals
__device__ float4 clj_dg;                  // cell diagonal
__device__ float4 clj_cinv;                // 8/diag per axis
__device__ float4 clj_sf[CLJ_NSHIFT];      // s * diag (f32, __fmul_rn)

// Slab prune: d2<=c2 forces shifted atom i into a cutoff-wide boundary slab.
__device__ __forceinline__ bool clj_alive_f(float xi, float yi, float zi, int sx,
                                            int sy, int sz, float dgx, float dgy,
                                            float dgz) {
  bool a = true;
  if (sx < 0) a = a && (xi >= dgx - 5.3f); else if (sx > 0) a = a && (xi <= 5.3f);
  if (sy < 0) a = a && (yi >= dgy - 5.3f); else if (sy > 0) a = a && (yi <= 5.3f);
  if (sz < 0) a = a && (zi >= dgz - 5.3f); else if (sz > 0) a = a && (zi <= 5.3f);
  return a;
}

// Candidate cell range on one axis (monotone-rounding safe, 0.14 slack).
__device__ __forceinline__ void clj_crange(float t, float ci, int& lo, int& hi) {
  lo = max(0, (int)(fmaxf(t - CLJ_R, 0.f) * ci));
  hi = min(7, (int)(fmaxf(t + CLJ_R, 0.f) * ci));
}

__device__ __forceinline__ unsigned clj_iscan(unsigned v, int lane) {
  for (int off = 1; off < 64; off <<= 1) {
    unsigned t = __shfl_up(v, off);
    if (lane >= off) v += t;
  }
  return v;
}

// --- L1: wrap + cell-id; zero cnt/flag/nalive; publish constants ------------
// frac = x @ inv(cell); frac -= floor(frac); w = frac @ cell   (f32 per-op RN)
__global__ __launch_bounds__(256) void clj_wrapbin(const float* __restrict__ coords,
                                                   const float* __restrict__ cell) {
  int i = blockIdx.x * blockDim.x + threadIdx.x;
  if (i >= CLJ_NATOMS) return;
  if (i == 0) {
    clj_flag = 0u;
    clj_nalive = 0u;
  }
#pragma unroll
  for (int k = 0; k < CLJ_NSHIFT; ++k) clj_cnt[(k << 13) + i] = 0u;  // coalesced

  float dgx = (float)sqrt((double)cell[0] * cell[0] + (double)cell[3] * cell[3] +
                          (double)cell[6] * cell[6]);
  float dgy = (float)sqrt((double)cell[1] * cell[1] + (double)cell[4] * cell[4] +
                          (double)cell[7] * cell[7]);
  float dgz = (float)sqrt((double)cell[2] * cell[2] + (double)cell[5] * cell[5] +
                          (double)cell[8] * cell[8]);
  float cix = 8.0f / dgx, ciy = 8.0f / dgy, ciz = 8.0f / dgz;
  if (i == 0) {
    clj_dg = make_float4(dgx, dgy, dgz, 0.f);
    clj_cinv = make_float4(cix, ciy, ciz, 0.f);
    for (int k = 0; k < CLJ_NSHIFT; ++k)
      clj_sf[k] = make_float4(__fmul_rn((float)clj_shifts[k][0], dgx),
                              __fmul_rn((float)clj_shifts[k][1], dgy),
                              __fmul_rn((float)clj_shifts[k][2], dgz), 0.f);
  }

  double a00 = cell[0], a01 = cell[1], a02 = cell[2];
  double a10 = cell[3], a11 = cell[4], a12 = cell[5];
  double a20 = cell[6], a21 = cell[7], a22 = cell[8];
  double det = a00 * (a11 * a22 - a12 * a21) - a01 * (a10 * a22 - a12 * a20) +
               a02 * (a10 * a21 - a11 * a20);
  double id = 1.0 / det;
  float inv[3][3];
  inv[0][0] = (float)((a11 * a22 - a12 * a21) * id);
  inv[0][1] = (float)(-(a01 * a22 - a02 * a21) * id);
  inv[0][2] = (float)((a01 * a12 - a02 * a11) * id);
  inv[1][0] = (float)(-(a10 * a22 - a12 * a20) * id);
  inv[1][1] = (float)((a00 * a22 - a02 * a20) * id);
  inv[1][2] = (float)(-(a00 * a12 - a02 * a10) * id);
  inv[2][0] = (float)((a10 * a21 - a11 * a20) * id);
  inv[2][1] = (float)(-(a00 * a21 - a01 * a20) * id);
  inv[2][2] = (float)((a00 * a11 - a01 * a10) * id);

  float x = coords[3 * i], y = coords[3 * i + 1], z = coords[3 * i + 2];
  float fr[3], w[3];
#pragma unroll
  for (int c = 0; c < 3; ++c) {
    float f = __fadd_rn(__fadd_rn(__fmul_rn(x, inv[0][c]), __fmul_rn(y, inv[1][c])),
                        __fmul_rn(z, inv[2][c]));
    fr[c] = __fsub_rn(f, floorf(f));
  }
#pragma unroll
  for (int c = 0; c < 3; ++c) {
    w[c] = __fadd_rn(
        __fadd_rn(__fmul_rn(fr[0], cell[0 * 3 + c]), __fmul_rn(fr[1], cell[1 * 3 + c])),
        __fmul_rn(fr[2], cell[2 * 3 + c]));
  }
  clj_pp[i] = make_float4(w[0], w[1], w[2], 0.0f);
  int cx = min(7, (int)(w[0] * cix));
  int cy = min(7, (int)(w[1] * ciy));
  int cz = min(7, (int)(w[2] * ciz));
  clj_cid[i] = (cz * 8 + cy) * 8 + cx;  // x fastest -> contiguous x-runs
}

// --- L2: block 0 builds hist+scan (cstart/cfill), sets flag; 15 other blocks
// spin (single lane) then all 16 scatter 512 atoms each + build alive list.
// Replay-safe: L1 re-zeroes flag/nalive before this kernel each replay. ------
__global__ __launch_bounds__(512) void clj_scatterfused() {
  __shared__ unsigned h[CLJ_NCELL];
  int tid = threadIdx.x;
  if (blockIdx.x == 0) {
    h[tid] = 0u;
    __syncthreads();
    for (int r = tid; r < CLJ_NATOMS; r += 512) atomicAdd(&h[clj_cid[r]], 1u);
    __syncthreads();
    unsigned v = h[tid];
    unsigned acc = v;
    for (int off = 1; off < CLJ_NCELL; off <<= 1) {
      unsigned a = (tid >= off) ? h[tid - off] : 0u;
      __syncthreads();
      acc += a;
      h[tid] = acc;
      __syncthreads();
    }
    clj_cstart[tid] = acc - v;
    atomicExch(&clj_cfill[tid], acc - v);
    if (tid == CLJ_NCELL - 1) clj_cstart[CLJ_NCELL] = acc;
    __threadfence();
    __syncthreads();
    if (tid == 0) atomicExch(&clj_flag, 1u);
  } else {
    if (tid == 0) {
      while (atomicAdd(&clj_flag, 0u) == 0u) __builtin_amdgcn_s_sleep(8);
    }
    __syncthreads();
    __threadfence();
  }
  // scatter (intra-cell order nondeterministic; output-invariant)
  int i = blockIdx.x * 512 + tid;
  float4 p = clj_pp[i];
  unsigned pos = atomicAdd(&clj_cfill[clj_cid[i]], 1u);
  float4 ps = p;
  ps.w = __int_as_float(i);
  clj_sorted[pos] = ps;

  // alive (k,i) row list (alist order nondeterministic; output-invariant)
  float4 dg = clj_dg;
  unsigned rows[CLJ_NSHIFT];
  int m = 0;
  rows[m++] = (unsigned)i;  // k = 0 always alive
#pragma unroll
  for (int k = 1; k < CLJ_NSHIFT; ++k) {
    if (clj_alive_f(p.x, p.y, p.z, clj_shifts[k][0], clj_shifts[k][1],
                    clj_shifts[k][2], dg.x, dg.y, dg.z))
      rows[m++] = (unsigned)((k << 13) + i);
  }
  unsigned base = atomicAdd(&clj_nalive, (unsigned)m);
  for (int q = 0; q < m; ++q) clj_alist[base + q] = rows[q];
}

// --- L3: count: persistent waves over ALIVE rows (balanced); per row:
// cell-list candidates -> LDS bitmask -> sorted compact j-list + count.
// Skip test is wave-uniform from the reconverged mask (round-14 lesson). -----
__global__ __launch_bounds__(512) void clj_count() {
  __shared__ uint4 smask[8][64];  // 1KB mask per wave
  int wslot = threadIdx.x >> 6;
  int lane = threadIdx.x & 63;
  unsigned* lm = (unsigned*)smask[wslot];
  unsigned na = clj_nalive;
  float4 cinv = clj_cinv;

  for (unsigned w = blockIdx.x * 8 + wslot; w < na; w += CLJ_PWAVES) {
    unsigned row = clj_alist[w];
    int k = row >> 13, i = row & (CLJ_NATOMS - 1);
    float4 sc = clj_sf[k];
    float4 pi = clj_pp[i];
    smask[wslot][lane] = make_uint4(0u, 0u, 0u, 0u);

    int xlo, xhi, ylo, yhi, zlo, zhi;
    clj_crange(__fadd_rn(pi.x, sc.x), cinv.x, xlo, xhi);
    clj_crange(__fadd_rn(pi.y, sc.y), cinv.y, ylo, yhi);
    clj_crange(__fadd_rn(pi.z, sc.z), cinv.z, zlo, zhi);

    for (int cz = zlo; cz <= zhi; ++cz) {
      for (int cy = ylo; cy <= yhi; ++cy) {
        int idb = (cz * 8 + cy) * 8;
        unsigned b = clj_cstart[idb + xlo], e = clj_cstart[idb + xhi + 1];
        for (unsigned t = b + lane; t < e; t += 64) {
          float4 pj = clj_sorted[t];
          int j = __float_as_int(pj.w);
          float dx = __fadd_rn(__fsub_rn(pi.x, pj.x), sc.x);
          float dy = __fadd_rn(__fsub_rn(pi.y, pj.y), sc.y);
          float dz = __fadd_rn(__fsub_rn(pi.z, pj.z), sc.z);
          float d2 = __fadd_rn(__fadd_rn(__fmul_rn(dx, dx), __fmul_rn(dy, dy)),
                               __fmul_rn(dz, dz));
          bool ok = (d2 <= CLJ_C2) && (k != 0 || i < j);
          if (ok) atomicOr(&lm[(unsigned)j >> 5], 1u << (j & 31));
        }
      }
    }
    __threadfence_block();  // drain LDS atomics; all lanes reconverged here

    const unsigned long long* mrow = (const unsigned long long*)lm;
    unsigned long long m0 = mrow[lane];       // j in [64*lane, 64*lane+64)
    unsigned long long m1 = mrow[64 + lane];  // j in [4096+64*lane, ...)
    if (__ballot((m0 | m1) != 0ull) == 0ull) continue;  // wave-uniform skip

    unsigned c0 = (unsigned)__popcll(m0), c1 = (unsigned)__popcll(m1);
    unsigned s0 = clj_iscan(c0, lane);
    unsigned T0 = __shfl(s0, 63);
    unsigned e0 = s0 - c0;
    unsigned s1 = clj_iscan(c1, lane);
    unsigned T1 = __shfl(s1, 63);
    unsigned e1 = T0 + s1 - c1;

    size_t jb = (size_t)row * CLJ_CAP;
    unsigned p = e0;
    unsigned long long m = m0;
    while (m) {
      int b = __ffsll((long long)m) - 1;
      m &= m - 1;
      if (p < CLJ_CAP) clj_jbuf[jb + p] = (lane << 6) + b;
      ++p;
    }
    p = e1;
    m = m1;
    while (m) {
      int b = __ffsll((long long)m) - 1;
      m &= m - 1;
      if (p < CLJ_CAP) clj_jbuf[jb + p] = ((64 + lane) << 6) + b;
      ++p;
    }
    if (lane == 0) clj_cnt[row] = min(T0 + T1, (unsigned)CLJ_CAP);
  }
}

// --- L4: per-1024-row tile exclusive scan + tile total ----------------------
__global__ __launch_bounds__(1024) void clj_s1() {
  __shared__ unsigned sd[1024];
  int t = threadIdx.x;
  int gid = blockIdx.x * 1024 + t;
  unsigned v = clj_cnt[gid];
  sd[t] = v;
  __syncthreads();
  unsigned acc = v;
  for (int off = 1; off < 1024; off <<= 1) {
    unsigned a = (t >= off) ? sd[t - off] : 0u;
    __syncthreads();
    acc += a;
    sd[t] = acc;
    __syncthreads();
  }
  clj_off[gid] = acc - v;
  if (t == 1023) clj_tot[blockIdx.x] = acc;
}

// --- L5: emit: persistent waves over alive rows; per row: reduce preceding
// tile totals (<=112, L2-hot) inline for the base, then lanes copy the compact
// j-list into [ i xP | j xP | (sx,sy,sz) xP ] coalesced ----------------------
__global__ __launch_bounds__(512) void clj_emit(int* __restrict__ out, int P) {
  int wslot = threadIdx.x >> 6;
  int lane = threadIdx.x & 63;
  unsigned na = clj_nalive;

  for (unsigned w = blockIdx.x * 8 + wslot; w < na; w += CLJ_PWAVES) {
    unsigned row = clj_alist[w];
    unsigned c = clj_cnt[row];  // wave-uniform load
    if (c == 0) continue;       // uniform branch
    int tile = row >> 10;       // 1024 rows per tile
    unsigned v = 0;
    if (lane < tile) v = clj_tot[lane];
    if (64 + lane < tile) v += clj_tot[64 + lane];
#pragma unroll
    for (int off = 32; off; off >>= 1) v += __shfl_down(v, off);
    unsigned tbase = __shfl(v, 0);

    unsigned off0 = clj_off[row] + tbase;
    int k = row >> 13, i = row & (CLJ_NATOMS - 1);
    int sx = clj_shifts[k][0], sy = clj_shifts[k][1], sz = clj_shifts[k][2];
    size_t jb = (size_t)row * CLJ_CAP;
    for (unsigned q = lane; q < c; q += 64) {
      unsigned p = off0 + q;
      if (p < (unsigned)P) {
        out[p] = i;
        out[P + p] = clj_jbuf[jb + q];
        unsigned sp = 2u * (unsigned)P + 3u * p;
        out[sp] = sx;
        out[sp + 1] = sy;
        out[sp + 2] = sz;
      }
    }
  }
}

extern "C" void kernel_launch(void* const* d_in, const int* in_sizes, int n_in,
                              void* d_out, int out_size, void* d_ws, size_t ws_size,
                              hipStream_t stream) {
  const float* coords = (const float*)d_in[1];  // (1, N, 3) f32
  const float* cell = (const float*)d_in[2];    // (3, 3) f32
  int P = out_size / 5;

  clj_wrapbin<<<CLJ_NATOMS / 256, 256, 0, stream>>>(coords, cell);
  clj_scatterfused<<<16, 512, 0, stream>>>();
  clj_count<<<CLJ_PWAVES / 8, 512, 0, stream>>>();
  clj_s1<<<CLJ_NTILE, 1024, 0, stream>>>();
  clj_emit<<<CLJ_PWAVES / 8, 512, 0, stream>>>((int*)d_out, P);
}